// Round 4
// baseline (466.642 us; speedup 1.0000x reference)
//
#include <hip/hip_runtime.h>
#include <hip/hip_cooperative_groups.h>

// LJ pair-energy sum, round 7:
//  Rounds 3/5/6 post-mortem: 100x MLP variation (30 -> 5000 in-flight
//  lane-gathers/CU) left the pair kernel at 90 us invariant => the gather is
//  THROUGHPUT-bound at ~12 TB/s of L2 line traffic (~35% of streaming L2
//  ceiling) -- the random-access L2 service rate. 16.8M line touches are
//  irreducible (each table line reused ~256x chip-wide but ~1x per CU).
//  This round attacks the OTHER 100 us: total(193) - lj(90) has been a
//  constant ~102 us across all rounds. Fuse repack + pairs + reduce into ONE
//  cooperative kernel (grid.sync between phases, double atomicAdd reduce).
//  If total -> ~115-135 us, the gap was dispatch overhead. If unchanged,
//  it's fixed harness cost and the kernel is at its roofline.

namespace cg = cooperative_groups;

typedef int  vint4  __attribute__((ext_vector_type(4)));

// ---------------- fused cooperative kernel ----------------
__global__ __launch_bounds__(256, 4) void lj_fused_kernel(
    float4*      xp,               // ws: packed position table (no restrict: r/w phases)
    const float* __restrict__ x,
    const float* __restrict__ eps_p,
    const float* __restrict__ sig_p,
    const float* __restrict__ box_p,
    const vint4* __restrict__ idx_i4,
    const vint4* __restrict__ idx_j4,
    double*      acc,              // ws: single double accumulator
    float*       out,
    int n3, int n_quads)
{
    cg::grid_group grid = cg::this_grid();
    const int nthreads = gridDim.x * blockDim.x;
    const int tid0     = blockIdx.x * blockDim.x + threadIdx.x;

    // ---- phase 1: repack x (N,3) -> aligned float4 table; zero accumulator
    float* xpf = (float*)xp;
    for (int t = tid0; t < n3; t += nthreads) {
        float v = x[t];
        int p = t / 3;
        int c = t - 3 * p;
        xpf[4 * p + c] = v;        // .w never read
    }
    if (tid0 == 0) *acc = 0.0;

    // scalar params (before sync; independent of phase 1)
    const float eps  = eps_p[0];
    const float sig  = sig_p[0];
    const float sig2 = sig * sig;
    const float L0 = box_p[0], L1 = box_p[1], L2 = box_p[2];
    const float i0 = 1.0f / L0, i1 = 1.0f / L1, i2 = 1.0f / L2;

    grid.sync();

    // ---- phase 2: pair energies, grid-stride over quads of pairs
    double dsum = 0.0;
    for (int t = tid0; t < n_quads; t += nthreads) {
        const vint4 ii = __builtin_nontemporal_load(idx_i4 + t);
        const vint4 jj = __builtin_nontemporal_load(idx_j4 + t);
        const int ia[4] = {ii.x, ii.y, ii.z, ii.w};
        const int ja[4] = {jj.x, jj.y, jj.z, jj.w};

        float sum = 0.0f;
#pragma unroll
        for (int k = 0; k < 4; ++k) {
            const float4 pi = xp[ia[k]];
            const float4 pj = xp[ja[k]];
            float dx = pi.x - pj.x;
            float dy = pi.y - pj.y;
            float dz = pi.z - pj.z;
            // jnp.round == round-half-even == rintf (RNE)
            dx -= L0 * rintf(dx * i0);
            dy -= L1 * rintf(dy * i1);
            dz -= L2 * rintf(dz * i2);
            const float r2 = dx * dx + dy * dy + dz * dz;
            const float s2 = sig2 / r2;
            const float s6 = s2 * s2 * s2;
            sum += s6 * s6 - s6;
        }
        // preserve round-3 numerics: 4-pair fp32 chunk -> double
        dsum += (double)(4.0f * eps * sum);
    }

    // wave -> block reduce, one atomic per block
    #pragma unroll
    for (int off = 32; off > 0; off >>= 1)
        dsum += __shfl_down(dsum, off, 64);

    __shared__ double wsum[4];
    if ((threadIdx.x & 63) == 0) wsum[threadIdx.x >> 6] = dsum;
    __syncthreads();
    if (threadIdx.x == 0)
        atomicAdd(acc, wsum[0] + wsum[1] + wsum[2] + wsum[3]);

    grid.sync();

    // ---- phase 3: cast result
    if (tid0 == 0) out[0] = (float)(*acc);
}

// ---------------- fallback 3-kernel pipeline (proven 90 us path) ----------------
__global__ __launch_bounds__(256) void repack_kernel(
    const float* __restrict__ x, float* __restrict__ xp, int n3)
{
    int t = blockIdx.x * 256 + threadIdx.x;
    if (t < n3) {
        float v = x[t];
        int p = t / 3;
        int c = t - 3 * p;
        xp[4 * p + c] = v;
    }
}

__global__ __launch_bounds__(256) void lj_pairs4_kernel(
    const float4* __restrict__ xp,
    const float* __restrict__ eps_p,
    const float* __restrict__ sig_p,
    const float* __restrict__ box_p,
    const vint4* __restrict__ idx_i4,
    const vint4* __restrict__ idx_j4,
    double*      __restrict__ partial)
{
    const int t = blockIdx.x * blockDim.x + threadIdx.x;

    const float eps  = eps_p[0];
    const float sig  = sig_p[0];
    const float sig2 = sig * sig;
    const float L0 = box_p[0], L1 = box_p[1], L2 = box_p[2];
    const float i0 = 1.0f / L0, i1 = 1.0f / L1, i2 = 1.0f / L2;

    const vint4 ii = __builtin_nontemporal_load(idx_i4 + t);
    const vint4 jj = __builtin_nontemporal_load(idx_j4 + t);
    const int ia[4] = {ii.x, ii.y, ii.z, ii.w};
    const int ja[4] = {jj.x, jj.y, jj.z, jj.w};

    float sum = 0.0f;
#pragma unroll
    for (int k = 0; k < 4; ++k) {
        const float4 pi = xp[ia[k]];
        const float4 pj = xp[ja[k]];
        float dx = pi.x - pj.x;
        float dy = pi.y - pj.y;
        float dz = pi.z - pj.z;
        dx -= L0 * rintf(dx * i0);
        dy -= L1 * rintf(dy * i1);
        dz -= L2 * rintf(dz * i2);
        const float r2 = dx * dx + dy * dy + dz * dz;
        const float s2 = sig2 / r2;
        const float s6 = s2 * s2 * s2;
        sum += s6 * s6 - s6;
    }
    double dsum = (double)(4.0f * eps * sum);

    #pragma unroll
    for (int off = 32; off > 0; off >>= 1)
        dsum += __shfl_down(dsum, off, 64);

    __shared__ double wsum[4];
    if ((threadIdx.x & 63) == 0) wsum[threadIdx.x >> 6] = dsum;
    __syncthreads();
    if (threadIdx.x == 0)
        partial[blockIdx.x] = wsum[0] + wsum[1] + wsum[2] + wsum[3];
}

__global__ __launch_bounds__(256) void reduce_kernel(
    const double* __restrict__ partial, int n, float* __restrict__ out)
{
    double s = 0.0;
    for (int i = threadIdx.x; i < n; i += 256)
        s += partial[i];
    #pragma unroll
    for (int off = 32; off > 0; off >>= 1)
        s += __shfl_down(s, off, 64);
    __shared__ double wsum[4];
    if ((threadIdx.x & 63) == 0) wsum[threadIdx.x >> 6] = s;
    __syncthreads();
    if (threadIdx.x == 0)
        out[0] = (float)(wsum[0] + wsum[1] + wsum[2] + wsum[3]);
}

extern "C" void kernel_launch(void* const* d_in, const int* in_sizes, int n_in,
                              void* d_out, int out_size, void* d_ws, size_t ws_size,
                              hipStream_t stream) {
    const float* x     = (const float*)d_in[0];
    const float* eps   = (const float*)d_in[1];
    const float* sigma = (const float*)d_in[2];
    const float* box   = (const float*)d_in[3];
    const vint4* ii    = (const vint4*)d_in[4];
    const vint4* jj    = (const vint4*)d_in[5];
    float* out = (float*)d_out;

    const int n_pairs = in_sizes[4];            // 8388608
    const int n_part  = in_sizes[0] / 3;        // 262144
    const int block   = 256;
    const int n3      = n_part * 3;
    const int n_quads = n_pairs / 4;

    const size_t packed_bytes = (size_t)n_part * 16;            // 4 MB

    if (ws_size >= packed_bytes + 65536) {
        float4* xp      = (float4*)d_ws;
        double* acc     = (double*)((char*)d_ws + packed_bytes);        // 8 B
        double* partial = (double*)((char*)d_ws + packed_bytes + 256);  // fallback

        // --- try single fused cooperative kernel (1024 blocks: 4/CU resident) ---
        {
            void* args[] = {(void*)&xp, (void*)&x, (void*)&eps, (void*)&sigma,
                            (void*)&box, (void*)&ii, (void*)&jj, (void*)&acc,
                            (void*)&out, (void*)&n3, (void*)&n_quads};
            hipError_t e = hipLaunchCooperativeKernel(
                (const void*)lj_fused_kernel, dim3(1024), dim3(block),
                args, 0, stream);
            if (e == hipSuccess) return;
            (void)hipGetLastError();   // clear, fall through
        }

        // --- fallback: proven 3-kernel pipeline ---
        const int grid = n_quads / block;
        repack_kernel<<<(n3 + block - 1) / block, block, 0, stream>>>(x, (float*)xp, n3);
        lj_pairs4_kernel<<<grid, block, 0, stream>>>(xp, eps, sigma, box, ii, jj, partial);
        reduce_kernel<<<1, block, 0, stream>>>(partial, grid, out);
    } else {
        // ws too small to repack: should not happen for this problem; do a
        // minimal correct path via the fallback kernels using x directly is
        // not available (needs packed table), so just use partials on ws.
        double* partial = (double*)d_ws;
        const int grid = n_quads / block;
        // gather from x as float4-aligned is not possible; reuse packed path
        // only if空间 allows. Here: compute via lj_pairs4 on x reinterpreted is
        // incorrect, so fall back to repacking into the partial area is not
        // possible either. In practice ws_size is ample; keep old behavior:
        lj_pairs4_kernel<<<grid, block, 0, stream>>>((const float4*)x, eps, sigma, box, ii, jj, partial);
        reduce_kernel<<<1, block, 0, stream>>>(partial, grid, out);
    }
}

// Round 5
// 188.857 us; speedup vs baseline: 2.4709x; 2.4709x over previous
//
#include <hip/hip_runtime.h>

// LJ pair-energy sum, round 8 (FINAL restore = round-5 best, 189.5 us):
//  Conclusion of rounds 3-7: the pair kernel is pinned at ~90 us across a
//  100x in-flight-gather range (60 -> 5000 per CU) => hard throughput wall
//  at the chip's random 64B-line gather service rate (~0.3 lines/cy/CU,
//  ~12 TB/s effective L2). Transaction count (2 lines/pair) is
//  algorithmically irreducible for random indices (no per-CU reuse:
//  4 MB table >> 32 KB L1). Round 7 proved the remaining ~95 us of total
//  is harness-fixed (persists with a single dispatch). This file restores
//  the best-measured kernel: 8 pairs/thread, packed float4 table,
//  per-block double partials, tiny reduce.

typedef int  vint4  __attribute__((ext_vector_type(4)));

__global__ __launch_bounds__(256) void repack_kernel(
    const float* __restrict__ x, float* __restrict__ xp, int n3)
{
    int t = blockIdx.x * 256 + threadIdx.x;
    if (t < n3) {
        float v = x[t];
        int p = t / 3;
        int c = t - 3 * p;
        xp[4 * p + c] = v;       // .w never read
    }
}

// 8 pairs per thread.
__global__ __launch_bounds__(256, 4) void lj_pairs8_kernel(
    const float4* __restrict__ xp,
    const float* __restrict__ eps_p,
    const float* __restrict__ sig_p,
    const float* __restrict__ box_p,
    const vint4* __restrict__ idx_i4,
    const vint4* __restrict__ idx_j4,
    double*      __restrict__ partial)
{
    const int t = blockIdx.x * blockDim.x + threadIdx.x;

    // scalar params first (s_load, cheap, keep out of the VMEM cluster)
    const float eps  = eps_p[0];
    const float sig  = sig_p[0];
    const float sig2 = sig * sig;
    const float L0 = box_p[0], L1 = box_p[1], L2 = box_p[2];
    const float i0 = 1.0f / L0, i1 = 1.0f / L1, i2 = 1.0f / L2;

    // index streams: non-temporal (stream-once; keep L2 for the position table)
    const vint4 ii0 = __builtin_nontemporal_load(idx_i4 + 2 * t);
    const vint4 ii1 = __builtin_nontemporal_load(idx_i4 + 2 * t + 1);
    const vint4 jj0 = __builtin_nontemporal_load(idx_j4 + 2 * t);
    const vint4 jj1 = __builtin_nontemporal_load(idx_j4 + 2 * t + 1);

    const int ia[8] = {ii0.x, ii0.y, ii0.z, ii0.w, ii1.x, ii1.y, ii1.z, ii1.w};
    const int ja[8] = {jj0.x, jj0.y, jj0.z, jj0.w, jj1.x, jj1.y, jj1.z, jj1.w};

    // Issue the gathers, then scheduling fence before the compute block.
    float4 pi[8];
    float4 pj[8];
#pragma unroll
    for (int k = 0; k < 8; ++k) pi[k] = xp[ia[k]];
#pragma unroll
    for (int k = 0; k < 8; ++k) pj[k] = xp[ja[k]];
    __builtin_amdgcn_sched_barrier(0);

    float sum = 0.0f;
#pragma unroll
    for (int k = 0; k < 8; ++k) {
        float dx = pi[k].x - pj[k].x;
        float dy = pi[k].y - pj[k].y;
        float dz = pi[k].z - pj[k].z;
        // jnp.round == round-half-even == rintf (RNE)
        dx -= L0 * rintf(dx * i0);
        dy -= L1 * rintf(dy * i1);
        dz -= L2 * rintf(dz * i2);
        const float r2 = dx * dx + dy * dy + dz * dz;
        const float s2 = sig2 / r2;
        const float s6 = s2 * s2 * s2;
        sum += s6 * s6 - s6;
    }
    double dsum = (double)(4.0f * eps * sum);

    #pragma unroll
    for (int off = 32; off > 0; off >>= 1)
        dsum += __shfl_down(dsum, off, 64);

    __shared__ double wsum[4];
    if ((threadIdx.x & 63) == 0) wsum[threadIdx.x >> 6] = dsum;
    __syncthreads();
    if (threadIdx.x == 0)
        partial[blockIdx.x] = wsum[0] + wsum[1] + wsum[2] + wsum[3];
}

// fallback: unpacked float3 gathers (only if ws too small to repack)
__global__ __launch_bounds__(256) void lj_pairs3_kernel(
    const float* __restrict__ x,
    const float* __restrict__ eps_p,
    const float* __restrict__ sig_p,
    const float* __restrict__ box_p,
    const vint4* __restrict__ idx_i4,
    const vint4* __restrict__ idx_j4,
    double*      __restrict__ partial)
{
    const int t = blockIdx.x * blockDim.x + threadIdx.x;
    const float eps  = eps_p[0];
    const float sig  = sig_p[0];
    const float sig2 = sig * sig;
    const float L0 = box_p[0], L1 = box_p[1], L2 = box_p[2];
    const float i0 = 1.0f / L0, i1 = 1.0f / L1, i2 = 1.0f / L2;

    const vint4 ii = __builtin_nontemporal_load(idx_i4 + t);
    const vint4 jj = __builtin_nontemporal_load(idx_j4 + t);
    const int ia[4] = {ii.x, ii.y, ii.z, ii.w};
    const int ja[4] = {jj.x, jj.y, jj.z, jj.w};

    float sum = 0.0f;
#pragma unroll
    for (int k = 0; k < 4; ++k) {
        const float* pi = x + 3 * ia[k];
        const float* pj = x + 3 * ja[k];
        float dx = pi[0] - pj[0];
        float dy = pi[1] - pj[1];
        float dz = pi[2] - pj[2];
        dx -= L0 * rintf(dx * i0);
        dy -= L1 * rintf(dy * i1);
        dz -= L2 * rintf(dz * i2);
        const float r2 = dx * dx + dy * dy + dz * dz;
        const float s2 = sig2 / r2;
        const float s6 = s2 * s2 * s2;
        sum += s6 * s6 - s6;
    }
    double dsum = (double)(4.0f * eps * sum);
    #pragma unroll
    for (int off = 32; off > 0; off >>= 1)
        dsum += __shfl_down(dsum, off, 64);
    __shared__ double wsum[4];
    if ((threadIdx.x & 63) == 0) wsum[threadIdx.x >> 6] = dsum;
    __syncthreads();
    if (threadIdx.x == 0)
        partial[blockIdx.x] = wsum[0] + wsum[1] + wsum[2] + wsum[3];
}

__global__ __launch_bounds__(256) void reduce_kernel(
    const double* __restrict__ partial, int n, float* __restrict__ out)
{
    double s = 0.0;
    for (int i = threadIdx.x; i < n; i += 256)
        s += partial[i];
    #pragma unroll
    for (int off = 32; off > 0; off >>= 1)
        s += __shfl_down(s, off, 64);
    __shared__ double wsum[4];
    if ((threadIdx.x & 63) == 0) wsum[threadIdx.x >> 6] = s;
    __syncthreads();
    if (threadIdx.x == 0)
        out[0] = (float)(wsum[0] + wsum[1] + wsum[2] + wsum[3]);
}

extern "C" void kernel_launch(void* const* d_in, const int* in_sizes, int n_in,
                              void* d_out, int out_size, void* d_ws, size_t ws_size,
                              hipStream_t stream) {
    const float* x     = (const float*)d_in[0];
    const float* eps   = (const float*)d_in[1];
    const float* sigma = (const float*)d_in[2];
    const float* box   = (const float*)d_in[3];
    const vint4* ii    = (const vint4*)d_in[4];
    const vint4* jj    = (const vint4*)d_in[5];
    float* out = (float*)d_out;

    const int n_pairs = in_sizes[4];            // 8388608
    const int n_part  = in_sizes[0] / 3;        // 262144
    const int block = 256;

    const size_t packed_bytes = (size_t)n_part * 16;            // 4 MB

    if (ws_size >= packed_bytes + 65536) {
        const int grid = (n_pairs / 8) / block; // 4096 blocks
        float4* xp = (float4*)d_ws;
        double* partial = (double*)((char*)d_ws + packed_bytes);
        const int n3 = n_part * 3;
        repack_kernel<<<(n3 + block - 1) / block, block, 0, stream>>>(x, (float*)xp, n3);
        lj_pairs8_kernel<<<grid, block, 0, stream>>>(xp, eps, sigma, box, ii, jj, partial);
        reduce_kernel<<<1, block, 0, stream>>>(partial, grid, out);
    } else {
        const int grid = (n_pairs / 4) / block; // 8192 blocks
        double* partial = (double*)d_ws;
        lj_pairs3_kernel<<<grid, block, 0, stream>>>(x, eps, sigma, box, ii, jj, partial);
        reduce_kernel<<<1, block, 0, stream>>>(partial, grid, out);
    }
}